// Round 7
// baseline (347.688 us; speedup 1.0000x reference)
//
#include <hip/hip_runtime.h>
#include <hip/hip_bf16.h>

#define BB 8
#define LL 1024
#define DD 512
#define NH 8
#define DH 64
#define CO 7
#define GK 64          // K for corr GEMM: f=1..32, (re,im) pairs; f=0 dropped (softmax-invariant)
#define MM 8192        // NH*LL rows per batch
#define PLS 72         // fused_pv LDS row stride: 144B = 16B-aligned rows -> ds_*_b128

typedef __hip_bfloat16 bf16;
typedef __attribute__((ext_vector_type(8))) short short8;
typedef __attribute__((ext_vector_type(4))) float floatx4;
typedef __attribute__((ext_vector_type(4))) unsigned short ushort4v;

__device__ __forceinline__ float b2f(bf16 v){ return __bfloat162float(v); }
__device__ __forceinline__ bf16 f2b(float v){ return __float2bfloat16(v); }
__device__ __forceinline__ unsigned short f2bu(float v){
    bf16 h = f2b(v); return *(unsigned short*)&h;
}
__device__ __forceinline__ float bu2f(unsigned short u){
    union{unsigned i; float f;} x; x.i = ((unsigned)u)<<16; return x.f;
}

// Decide whether global float data is genuine f32 (flag=1) or packed bf16 (flag=0).
__global__ void sniff_kernel(const unsigned* __restrict__ x, int* __restrict__ flag){
    unsigned u = x[threadIdx.x];
    int e = (u >> 23) & 0xff;
    int sane = (e >= 32 && e <= 200) ? 1 : 0;
    unsigned long long m = __ballot(sane);
    if(threadIdx.x == 0) *flag = (__popcll(m) >= 32) ? 1 : 0;
}

// Merged init: blocks 0..127 -> Tg (trig), 128..135 -> Tw (twiddle), 136..142 -> pwT.
__global__ __launch_bounds__(512) void prep_kernel(bf16* __restrict__ Tg,
                                                   bf16* __restrict__ Tw,
                                                   const void* __restrict__ pwv,
                                                   const int* __restrict__ flag,
                                                   float* __restrict__ pwT){
    int blk = blockIdx.x, tid = threadIdx.x;
    if(blk < 128){
        int t = blk*8 + (tid >> 6), k = tid & 63;
        int f = (k >> 1) + 1;
        int ph = (f*t) & 1023;
        float s, c;
        __sincosf((float)ph * (6.28318530717958647692f/1024.f), &s, &c);
        Tg[(size_t)t*GK + k] = f2b((k & 1) ? s : c);
    } else if(blk < 136){
        int idx = (blk-128)*512 + tid;      // 4096 entries
        int k = idx >> 6, j = idx & 63;
        int f = (k >> 1) + 1;
        int ph = (f*j) & 63;
        float s, c;
        __sincosf((float)ph * (6.28318530717958647692f/64.f), &s, &c);
        Tw[(size_t)k*64 + j] = f2b((k & 1) ? -s : c);
    } else {
        int c = blk - 136, d = tid;
        bool f32 = (*flag != 0);
        float v = f32 ? ((const float*)pwv)[(size_t)d*CO + c]
                      : b2f(((const bf16*)pwv)[(size_t)d*CO + c]);
        pwT[(size_t)c*DD + d] = v;
    }
}

// Fused MA25 + embedding: block = one (b,l) row, 512 threads (= DD).
// Lanes 0..6 compute the 7-channel moving average in-block (kills the ma7
// kernel + xs/xm global round-trip), then all 512 threads do the embed.
__global__ __launch_bounds__(512) void embed2f(const void* __restrict__ xv,
                                               const void* __restrict__ wv,
                                               const void* __restrict__ bv,
                                               const int* __restrict__ flag,
                                               bf16* __restrict__ seas,
                                               bf16* __restrict__ trend,
                                               int accumulate){
    __shared__ float sxs[8], sxm[8];
    bool f32 = (*flag != 0);
    int row = blockIdx.x;                // b*1024 + l
    int l = row & (LL-1), b = row >> 10;
    int lane = threadIdx.x;
    int lo = l-12; if(lo<0) lo=0;
    int hi = l+12; if(hi>LL-1) hi=LL-1;
    if(lane < 7){
        float s = 0.f, xc;
        if(f32){
            const float* x = (const float*)xv + ((size_t)b*LL)*7 + lane;
            for(int m=lo;m<=hi;m++) s += x[(size_t)m*7];
            xc = x[(size_t)l*7];
        }else{
            const bf16* x = (const bf16*)xv + ((size_t)b*LL)*7 + lane;
            for(int m=lo;m<=hi;m++) s += b2f(x[(size_t)m*7]);
            xc = b2f(x[(size_t)l*7]);
        }
        float ma = s*(1.f/25.f);
        sxm[lane] = ma;
        sxs[lane] = xc - ma;
    }
    __syncthreads();
    int d = lane;
    float cf = (float)(hi-lo+1) * (1.f/25.f);
    float wcol[7], bias;
    if(f32){
        const float* w = (const float*)wv;
        #pragma unroll
        for(int i=0;i<7;i++) wcol[i] = w[i*DD + d];
        bias = ((const float*)bv)[d];
    }else{
        const bf16* w = (const bf16*)wv;
        #pragma unroll
        for(int i=0;i<7;i++) wcol[i] = b2f(w[i*DD + d]);
        bias = b2f(((const bf16*)bv)[d]);
    }
    float sa = 0.f, ta = 0.f;
    #pragma unroll
    for(int i=0;i<7;i++){
        sa += sxs[i]*wcol[i];
        ta += sxm[i]*wcol[i];
    }
    int idx = row*DD + d;
    seas[idx] = f2b(sa + bias*(1.f-cf));
    float t = ta + bias*cf;
    if(accumulate) t += b2f(trend[idx]);
    trend[idx] = f2b(t);
}

// MFMA DFT: rows = (b,l,h) flattened [65536 x 64], Tw [64 comps x 64 j].
// Output transpose through LDS; coalesced short8 stores (R6, kept).
__global__ __launch_bounds__(256) void dft2(const bf16* __restrict__ qg,
                                            const bf16* __restrict__ kg,
                                            const bf16* __restrict__ Tw,
                                            bf16* __restrict__ Ab,
                                            int same_qk){
    __shared__ __align__(16) unsigned short Tl[64][68];
    int tid = threadIdx.x, wv = tid >> 6, lane = tid & 63;
    int qd = lane >> 4, n = lane & 15;
    int m0 = blockIdx.x*64 + wv*16;     // wave's 16 global rows (= 2 l x 8 h)
    const short* qp = (const short*)qg;
    const short* kp = (const short*)kg;
    const short* tw = (const short*)Tw;
    short8 aq0 = *(const short8*)&qp[(size_t)(m0+n)*64 + qd*8];
    short8 aq1 = *(const short8*)&qp[(size_t)(m0+n)*64 + 32 + qd*8];
    short8 bw[4][2];
    #pragma unroll
    for(int nt=0;nt<4;nt++){
        bw[nt][0] = *(const short8*)&tw[(size_t)(nt*16+n)*64 + qd*8];
        bw[nt][1] = *(const short8*)&tw[(size_t)(nt*16+n)*64 + 32 + qd*8];
    }
    floatx4 dq[4], dk[4];
    #pragma unroll
    for(int nt=0;nt<4;nt++){
        floatx4 a = {};
        a = __builtin_amdgcn_mfma_f32_16x16x32_bf16(aq0, bw[nt][0], a, 0,0,0);
        a = __builtin_amdgcn_mfma_f32_16x16x32_bf16(aq1, bw[nt][1], a, 0,0,0);
        dq[nt] = a;
    }
    if(same_qk){
        #pragma unroll
        for(int nt=0;nt<4;nt++) dk[nt] = dq[nt];
    }else{
        short8 ak0 = *(const short8*)&kp[(size_t)(m0+n)*64 + qd*8];
        short8 ak1 = *(const short8*)&kp[(size_t)(m0+n)*64 + 32 + qd*8];
        #pragma unroll
        for(int nt=0;nt<4;nt++){
            floatx4 a = {};
            a = __builtin_amdgcn_mfma_f32_16x16x32_bf16(ak0, bw[nt][0], a, 0,0,0);
            a = __builtin_amdgcn_mfma_f32_16x16x32_bf16(ak1, bw[nt][1], a, 0,0,0);
            dk[nt] = a;
        }
    }
    #pragma unroll
    for(int nt=0;nt<4;nt++){
        float o[4];
        #pragma unroll
        for(int r=0;r<4;r++){
            float a  = dq[nt][r], pa = __shfl_xor(a, 1);
            float c  = dk[nt][r], pc = __shfl_xor(c, 1);
            o[r] = (n & 1) ? (pa*c - a*pc) : (a*c + pa*pc);
        }
        float s = o[0]+o[1]+o[2]+o[3];
        s += __shfl_xor(s, 16);          // pair qd<->qd^1: all 8 h of same l
        float mean = s*0.125f;
        #pragma unroll
        for(int r=0;r<4;r++)
            Tl[wv*16 + qd*4 + r][nt*16 + n] = f2bu((o[r]-mean)*(1.f/512.f));
    }
    __syncthreads();
    // coalesced store: thread t -> h-slab (t>>5), row l_loc ((t&31)>>2), 32B chunk (t&3)
    int h2 = tid >> 5, lloc = (tid & 31) >> 2, c4 = tid & 3;
    int lr = lloc*8 + h2;
    int bI = blockIdx.x >> 7;
    int l  = (blockIdx.x & 127)*8 + lloc;
    union { ushort4v h[4]; short8 s[2]; } w;
    const unsigned short* src = &Tl[lr][c4*16];
    w.h[0] = *(const ushort4v*)(src);
    w.h[1] = *(const ushort4v*)(src+4);
    w.h[2] = *(const ushort4v*)(src+8);
    w.h[3] = *(const ushort4v*)(src+12);
    short* dp = (short*)Ab + ((size_t)bI*MM + (size_t)h2*LL + l)*GK + c4*16;
    *(short8*)dp       = w.s[0];
    *(short8*)(dp + 8) = w.s[1];
}

// Row "stats": writes -ln(S_m) directly (fused_pv uses it as MFMA C-init).
__global__ __launch_bounds__(256) void rowstats3(const bf16* __restrict__ Ab,
                                                 const bf16* __restrict__ Tg,
                                                 float* __restrict__ rs){
    __shared__ float red[4][64];
    int tid = threadIdx.x, wv = tid >> 6, lane = tid & 63;
    int q = lane >> 4, n = lane & 15;
    int m0 = blockIdx.x*64, bloc = blockIdx.y;
    const short* Abase = (const short*)(Ab + ((size_t)bloc*MM)*GK);
    const short* Tb = (const short*)Tg;
    short8 af[4][2];
    #pragma unroll
    for(int mg=0;mg<4;mg++){
        af[mg][0] = *(const short8*)&Abase[(size_t)(m0+mg*16+n)*GK + q*8];
        af[mg][1] = *(const short8*)&Abase[(size_t)(m0+mg*16+n)*GK + 32 + q*8];
    }
    float s[4][4] = {};
    #pragma unroll
    for(int nt=0;nt<16;nt++){
        int t = wv*256 + nt*16 + n;
        short8 b0 = *(const short8*)&Tb[(size_t)t*GK + q*8];
        short8 b1 = *(const short8*)&Tb[(size_t)t*GK + 32 + q*8];
        #pragma unroll
        for(int mg=0;mg<4;mg++){
            floatx4 d = {};
            d = __builtin_amdgcn_mfma_f32_16x16x32_bf16(af[mg][0], b0, d, 0,0,0);
            d = __builtin_amdgcn_mfma_f32_16x16x32_bf16(af[mg][1], b1, d, 0,0,0);
            #pragma unroll
            for(int r=0;r<4;r++) s[mg][r] += __expf(d[r]);
        }
    }
    #pragma unroll
    for(int o=1;o<16;o<<=1)
        #pragma unroll
        for(int mg=0;mg<4;mg++)
            #pragma unroll
            for(int r=0;r<4;r++) s[mg][r] += __shfl_xor(s[mg][r], o, 64);
    if(n == 0){
        #pragma unroll
        for(int mg=0;mg<4;mg++)
            #pragma unroll
            for(int r=0;r<4;r++) red[wv][mg*16 + q*4 + r] = s[mg][r];
    }
    __syncthreads();
    if(tid < 64)
        rs[(size_t)bloc*MM + m0 + tid] =
            -__logf(red[0][tid]+red[1][tid]+red[2][tid]+red[3][tid]);
}

// V-transpose: Vt[(b*8+h)*64 + c][j] = v[b][j][h*64+c]  (LDS-tiled, coalesced both sides)
__global__ __launch_bounds__(256) void vt_kernel(const bf16* __restrict__ v,
                                                 bf16* __restrict__ vt){
    __shared__ unsigned short T2[64][68];   // [c][j_loc]
    int jc = blockIdx.x, h = blockIdx.y, b = blockIdx.z;
    int tid = threadIdx.x;
    const unsigned short* src = (const unsigned short*)v + ((size_t)b*LL)*DD + (size_t)h*DH;
    int cq = tid & 15, jq = tid >> 4;       // thread: c-quad cq*4, 4 j rows
    #pragma unroll
    for(int jr=0;jr<4;jr++){
        int jl = jq*4 + jr;
        ushort4v vv = *(const ushort4v*)&src[(size_t)(jc*64 + jl)*DD + cq*4];
        T2[cq*4+0][jl] = vv.x;
        T2[cq*4+1][jl] = vv.y;
        T2[cq*4+2][jl] = vv.z;
        T2[cq*4+3][jl] = vv.w;
    }
    __syncthreads();
    int j4 = tid & 15, ct = tid >> 4;
    unsigned short* dstb = (unsigned short*)vt + ((size_t)(b*NH + h))*64*LL + (size_t)jc*64;
    #pragma unroll
    for(int cc=0;cc<4;cc++){
        int c = cc*16 + ct;
        *(ushort4v*)&dstb[(size_t)c*LL + j4*4] = *(const ushort4v*)&T2[c][j4*4];
    }
}

// Fused corr-recompute + softmax + PV (R5 structure, R7: LDS row stride 72 so
// every fragment access is a provable ds_*_b128 -- cuts DS-pipe ops ~60->~40
// per wave per iter; fragment reads <=2-way banked, staging writes ~8-way on
// the minority path).
__global__ __launch_bounds__(256, 2) void fused_pv(const bf16* __restrict__ Ab,
                                                   const bf16* __restrict__ Tg,
                                                   const float* __restrict__ rs,
                                                   const bf16* __restrict__ vt,
                                                   bf16* __restrict__ dst){
    __shared__ __align__(16) unsigned short AbS[2][64][PLS];  // [buf][j_loc][k]
    __shared__ __align__(16) unsigned short VsS[2][64][PLS];  // [buf][c][j_loc]
    __shared__ __align__(16) unsigned short Pl[128][PLS];     // [i_loc][j_loc] wave-private rows
    __shared__ float stS[LL];                                 // -ln(S_j)
    int tid = threadIdx.x, wv = tid >> 6, lane = tid & 63;
    int q = lane >> 4, n = lane & 15;
    int id = blockIdx.x;                 // 0..511
    int xcd = id & 7, p = id >> 3;       // p: 0..63
    int pair = xcd*8 + (p & 7);          // all 8 i-splits of a pair on one XCD
    int i0 = (p >> 3) * 128;             // 8 i-splits x 128 rows
    int h = pair & 7, bloc = pair >> 3;
    const short* Abase = (const short*)(Ab + ((size_t)bloc*MM + (size_t)h*LL)*GK);
    const short* Tb = (const short*)Tg;
    const float* rsb = rs + (size_t)bloc*MM + (size_t)h*LL;
    const short* vtb = (const short*)(vt + (size_t)pair*64*LL);

    // stage -lnS once (coalesced float4)
    *(floatx4*)&stS[tid*4] = *(const floatx4*)&rsb[tid*4];

    // Tg fragments: 2 i-tiles per wave
    short8 tgf[2][2];
    #pragma unroll
    for(int t2=0;t2<2;t2++){
        tgf[t2][0] = *(const short8*)&Tb[(size_t)(i0+wv*32+t2*16+n)*GK + q*8];
        tgf[t2][1] = *(const short8*)&Tb[(size_t)(i0+wv*32+t2*16+n)*GK + 32 + q*8];
    }

    // staging map: thread -> row srow (0..63), 32B chunk sc (shorts)
    int srow = tid >> 2, sc = (tid & 3) * 16;
    const short* agp = &Abase[(size_t)srow*GK + sc];   // Ab[j0+srow][sc..]
    const short* vgp = &vtb[(size_t)srow*LL + sc];     // Vt[srow][j0+sc..]

    // prologue: stage j-tile 0 into buffer 0 (16B-aligned b128 stores)
    {
        short8 a0 = *(const short8*)agp;
        short8 a1 = *(const short8*)(agp+8);
        short8 v0 = *(const short8*)vgp;
        short8 v1 = *(const short8*)(vgp+8);
        *(short8*)&AbS[0][srow][sc]   = a0;
        *(short8*)&AbS[0][srow][sc+8] = a1;
        *(short8*)&VsS[0][srow][sc]   = v0;
        *(short8*)&VsS[0][srow][sc+8] = v1;
    }
    __syncthreads();

    floatx4 acc[4][2] = {};
    int cur = 0;
    for(int it=0; it<16; ++it){
        int j0 = it*64;
        // issue next-tile global loads EARLY (consumed after ~full iter of compute)
        short8 na0, na1, nv0, nv1;
        if(it < 15){
            na0 = *(const short8*)(agp + (size_t)(j0+64)*GK);
            na1 = *(const short8*)(agp + (size_t)(j0+64)*GK + 8);
            nv0 = *(const short8*)(vgp + (j0+64));
            nv1 = *(const short8*)(vgp + (j0+64) + 8);
        }
        // corr: P[j][i] = exp(corr - lnS_j); A-frags from LDS (b128), shared across i-tiles
        #pragma unroll
        for(int tj=0;tj<4;tj++){
            short8 a0 = *(const short8*)&AbS[cur][tj*16+n][q*8];
            short8 a1 = *(const short8*)&AbS[cur][tj*16+n][32+q*8];
            floatx4 c0 = *(const floatx4*)&stS[j0 + tj*16 + q*4];
            #pragma unroll
            for(int t2=0;t2<2;t2++){
                floatx4 d = c0;
                d = __builtin_amdgcn_mfma_f32_16x16x32_bf16(a0, tgf[t2][0], d, 0,0,0);
                d = __builtin_amdgcn_mfma_f32_16x16x32_bf16(a1, tgf[t2][1], d, 0,0,0);
                ushort4v pk;
                pk.x = f2bu(__expf(d[0]));
                pk.y = f2bu(__expf(d[1]));
                pk.z = f2bu(__expf(d[2]));
                pk.w = f2bu(__expf(d[3]));
                *(ushort4v*)&Pl[wv*32 + t2*16 + n][tj*16 + q*4] = pk;
            }
        }
        // PV: out^T[c][i]; va from LDS VsS (b128), pf wave-private (b128)
        #pragma unroll
        for(int kc=0;kc<2;kc++){
            short8 va[4];
            #pragma unroll
            for(int cs=0;cs<4;cs++)
                va[cs] = *(const short8*)&VsS[cur][cs*16+n][kc*32+q*8];
            #pragma unroll
            for(int t2=0;t2<2;t2++){
                short8 pf = *(const short8*)&Pl[wv*32 + t2*16 + n][kc*32 + q*8];
                #pragma unroll
                for(int cs=0;cs<4;cs++)
                    acc[cs][t2] = __builtin_amdgcn_mfma_f32_16x16x32_bf16(va[cs], pf, acc[cs][t2], 0,0,0);
            }
        }
        // write next stage LATE (global latency hidden under compute), then barrier
        if(it < 15){
            int nb = cur ^ 1;
            *(short8*)&AbS[nb][srow][sc]   = na0;
            *(short8*)&AbS[nb][srow][sc+8] = na1;
            *(short8*)&VsS[nb][srow][sc]   = nv0;
            *(short8*)&VsS[nb][srow][sc+8] = nv1;
        }
        __syncthreads();
        cur ^= 1;
    }
    // D[c][i]: c = cs*16 + q*4 + r, i = i0 + wv*32 + t2*16 + n
    bf16* db = dst + (size_t)bloc*LL*DD;
    #pragma unroll
    for(int t2=0;t2<2;t2++){
        int i = i0 + wv*32 + t2*16 + n;
        #pragma unroll
        for(int cs=0;cs<4;cs++){
            #pragma unroll
            for(int r=0;r<4;r++){
                int c = cs*16 + q*4 + r;
                db[(size_t)c*MM + h*LL + i] = f2b(acc[cs][t2][r]);
            }
        }
    }
}

// out = (seas + trend_sum) @ proj_w + proj_b, using pre-transposed pwT (f32).
__global__ __launch_bounds__(64) void final_kernel(const bf16* __restrict__ s,
                                                   const bf16* __restrict__ t,
                                                   const float* __restrict__ pwT,
                                                   const void* __restrict__ pbv,
                                                   const int* __restrict__ flag,
                                                   void* __restrict__ outv){
    bool f32 = (*flag != 0);
    int row = blockIdx.x;
    int lane = threadIdx.x;
    const short* sr = (const short*)s + (size_t)row*DD;
    const short* tr = (const short*)t + (size_t)row*DD;
    int j0 = lane*8;
    union { short8 v; unsigned short u[8]; } s8, t8;
    s8.v = *(const short8*)&sr[j0];
    t8.v = *(const short8*)&tr[j0];
    float dv[8];
    #pragma unroll
    for(int jj=0;jj<8;jj++) dv[jj] = bu2f(s8.u[jj]) + bu2f(t8.u[jj]);
    float acc[CO];
    #pragma unroll
    for(int c=0;c<CO;c++){
        floatx4 w0 = *(const floatx4*)&pwT[(size_t)c*DD + j0];
        floatx4 w1 = *(const floatx4*)&pwT[(size_t)c*DD + j0 + 4];
        acc[c] = dv[0]*w0[0] + dv[1]*w0[1] + dv[2]*w0[2] + dv[3]*w0[3]
               + dv[4]*w1[0] + dv[5]*w1[1] + dv[6]*w1[2] + dv[7]*w1[3];
    }
    #pragma unroll
    for(int c=0;c<CO;c++){
        float vsum = acc[c];
        for(int off=32;off;off>>=1) vsum += __shfl_down(vsum,off,64);
        if(lane==0){
            float bias = f32 ? ((const float*)pbv)[c] : b2f(((const bf16*)pbv)[c]);
            float o = vsum + bias;
            if(f32) ((float*)outv)[(size_t)row*CO + c] = o;
            else    ((bf16*)outv)[(size_t)row*CO + c] = f2b(o);
        }
    }
}

extern "C" void kernel_launch(void* const* d_in, const int* in_sizes, int n_in,
                              void* d_out, int out_size, void* d_ws, size_t ws_size,
                              hipStream_t stream){
    const void* x_enc  = d_in[0];
    const void* x_dec  = d_in[2];
    const void* enc_w  = d_in[4];
    const void* enc_b  = d_in[5];
    const void* dec_w  = d_in[6];
    const void* dec_b  = d_in[7];
    const void* proj_w = d_in[8];
    const void* proj_b = d_in[9];

    int*  flag = (int*)d_ws;
    const size_t NE = (size_t)BB*LL*DD;
    bf16* A  = (bf16*)((char*)d_ws + 1024);
    bf16* Bf = A  + NE;
    bf16* C  = Bf + NE;
    bf16* T  = C  + NE;
    bf16* Tg = T  + NE;                              // [1024][64]
    bf16* Tw = Tg + (size_t)LL*GK;                   // [64][64]
    float* xs = (float*)(Tw + 64*64);                // (unused; layout kept)
    float* xm = xs + (size_t)BB*LL*7;
    bf16* Ab  = (bf16*)(xm + (size_t)BB*LL*7);       // [BB][MM][GK]
    float* rs = (float*)(Ab + (size_t)BB*MM*GK);     // [BB][MM], holds -ln(S)
    bf16* Vt  = (bf16*)(rs + (size_t)BB*MM);         // [BB*NH*64][LL]
    float* pwT = (float*)(Vt + (size_t)BB*NH*64*LL); // [CO][DD]

    sniff_kernel<<<1,64,0,stream>>>((const unsigned*)x_enc, flag);
    prep_kernel<<<143,512,0,stream>>>(Tg, Tw, proj_w, flag, pwT);

    auto autocorr = [&](const bf16* q, const bf16* kv, bf16* dst){
        vt_kernel<<<dim3(16, NH, BB), 256, 0, stream>>>(kv, Vt);
        dft2<<<1024, 256, 0, stream>>>(q, kv, Tw, Ab, (q==kv) ? 1 : 0);
        rowstats3<<<dim3(128, BB), 256, 0, stream>>>(Ab, Tg, rs);
        fused_pv<<<512, 256, 0, stream>>>(Ab, Tg, rs, Vt, dst);
    };

    embed2f<<<BB*LL,512,0,stream>>>(x_enc, enc_w, enc_b, flag, A, T, 0);
    autocorr(A, A, Bf);      // layer 1 -> Bf
    autocorr(Bf, Bf, A);     // layer 2 -> A (= enc_seasonal out)

    embed2f<<<BB*LL,512,0,stream>>>(x_dec, dec_w, dec_b, flag, Bf, T, 1);
    autocorr(Bf, A, C);      // cross layer -> C

    final_kernel<<<BB*LL,64,0,stream>>>(C, T, pwT, proj_b, flag, d_out);
}

// Round 8
// 309.677 us; speedup vs baseline: 1.1227x; 1.1227x over previous
//
#include <hip/hip_runtime.h>
#include <hip/hip_bf16.h>

#define BB 8
#define LL 1024
#define DD 512
#define NH 8
#define DH 64
#define CO 7
#define GK 64          // K for corr GEMM: f=1..32, (re,im) pairs; f=0 dropped (softmax-invariant)
#define MM 8192        // NH*LL rows per batch

typedef __hip_bfloat16 bf16;
typedef __attribute__((ext_vector_type(8))) short short8;
typedef __attribute__((ext_vector_type(4))) float floatx4;
typedef __attribute__((ext_vector_type(4))) unsigned short ushort4v;

__device__ __forceinline__ float b2f(bf16 v){ return __bfloat162float(v); }
__device__ __forceinline__ bf16 f2b(float v){ return __float2bfloat16(v); }
__device__ __forceinline__ unsigned short f2bu(float v){
    bf16 h = f2b(v); return *(unsigned short*)&h;
}
__device__ __forceinline__ float bu2f(unsigned short u){
    union{unsigned i; float f;} x; x.i = ((unsigned)u)<<16; return x.f;
}

// Decide whether global float data is genuine f32 (flag=1) or packed bf16 (flag=0).
__global__ void sniff_kernel(const unsigned* __restrict__ x, int* __restrict__ flag){
    unsigned u = x[threadIdx.x];
    int e = (u >> 23) & 0xff;
    int sane = (e >= 32 && e <= 200) ? 1 : 0;
    unsigned long long m = __ballot(sane);
    if(threadIdx.x == 0) *flag = (__popcll(m) >= 32) ? 1 : 0;
}

// Merged init: blocks 0..127 -> Tg (trig), 128..135 -> Tw (twiddle), 136..142 -> pwT.
__global__ __launch_bounds__(512) void prep_kernel(bf16* __restrict__ Tg,
                                                   bf16* __restrict__ Tw,
                                                   const void* __restrict__ pwv,
                                                   const int* __restrict__ flag,
                                                   float* __restrict__ pwT){
    int blk = blockIdx.x, tid = threadIdx.x;
    if(blk < 128){
        int t = blk*8 + (tid >> 6), k = tid & 63;
        int f = (k >> 1) + 1;
        int ph = (f*t) & 1023;
        float s, c;
        __sincosf((float)ph * (6.28318530717958647692f/1024.f), &s, &c);
        Tg[(size_t)t*GK + k] = f2b((k & 1) ? s : c);
    } else if(blk < 136){
        int idx = (blk-128)*512 + tid;      // 4096 entries
        int k = idx >> 6, j = idx & 63;
        int f = (k >> 1) + 1;
        int ph = (f*j) & 63;
        float s, c;
        __sincosf((float)ph * (6.28318530717958647692f/64.f), &s, &c);
        Tw[(size_t)k*64 + j] = f2b((k & 1) ? -s : c);
    } else {
        int c = blk - 136, d = tid;
        bool f32 = (*flag != 0);
        float v = f32 ? ((const float*)pwv)[(size_t)d*CO + c]
                      : b2f(((const bf16*)pwv)[(size_t)d*CO + c]);
        pwT[(size_t)c*DD + d] = v;
    }
}

// moving average over the 7-channel input: xm = MA25(x), xs = x - xm  (f32 out)
__global__ __launch_bounds__(256) void ma7_kernel(const void* __restrict__ xv,
                                                  const int* __restrict__ flag,
                                                  float* __restrict__ xs,
                                                  float* __restrict__ xm){
    int idx = blockIdx.x*256 + threadIdx.x;
    if(idx >= BB*LL*7) return;
    bool f32 = (*flag != 0);
    int i = idx % 7;
    int row = idx / 7;
    int l = row & (LL-1);
    int b = row >> 10;
    int lo = l-12; if(lo<0) lo=0;
    int hi = l+12; if(hi>LL-1) hi=LL-1;
    float s = 0.f, xc;
    if(f32){
        const float* x = (const float*)xv + ((size_t)b*LL)*7 + i;
        for(int m=lo;m<=hi;m++) s += x[(size_t)m*7];
        xc = x[(size_t)l*7];
    }else{
        const bf16* x = (const bf16*)xv + ((size_t)b*LL)*7 + i;
        for(int m=lo;m<=hi;m++) s += b2f(x[(size_t)m*7]);
        xc = b2f(x[(size_t)l*7]);
    }
    float ma = s*(1.f/25.f);
    xm[idx] = ma;
    xs[idx] = xc - ma;
}

// seas[b,l,d] = xs@W + bias*(1-cnt/25); trend = xm@W + bias*cnt/25 (+= if accumulate)
// row is BLOCK-UNIFORM (row = blockIdx>>1) so the 14 xs/xm loads are s_loads.
__global__ __launch_bounds__(256) void embed2_kernel(const float* __restrict__ xs,
                                                     const float* __restrict__ xm,
                                                     const void* __restrict__ wv,
                                                     const void* __restrict__ bv,
                                                     const int* __restrict__ flag,
                                                     bf16* __restrict__ seas,
                                                     bf16* __restrict__ trend,
                                                     int accumulate){
    bool f32 = (*flag != 0);
    int row = blockIdx.x >> 1;                       // uniform per block (SGPR)
    int d = ((blockIdx.x & 1) << 8) + threadIdx.x;
    int idx = row*DD + d;
    int l = row & (LL-1);
    int lo = l-12; if(lo<0) lo=0;
    int hi = l+12; if(hi>LL-1) hi=LL-1;
    float cf = (float)(hi-lo+1) * (1.f/25.f);
    float wcol[7], bias;
    if(f32){
        const float* w = (const float*)wv;
        #pragma unroll
        for(int i=0;i<7;i++) wcol[i] = w[i*DD + d];
        bias = ((const float*)bv)[d];
    }else{
        const bf16* w = (const bf16*)wv;
        #pragma unroll
        for(int i=0;i<7;i++) wcol[i] = b2f(w[i*DD + d]);
        bias = b2f(((const bf16*)bv)[d]);
    }
    float sa = 0.f, ta = 0.f;
    #pragma unroll
    for(int i=0;i<7;i++){
        sa += xs[row*7+i]*wcol[i];                   // uniform addr -> s_load
        ta += xm[row*7+i]*wcol[i];
    }
    seas[idx] = f2b(sa + bias*(1.f-cf));
    float t = ta + bias*cf;
    if(accumulate) t += b2f(trend[idx]);
    trend[idx] = f2b(t);
}

// MFMA DFT: rows = (b,l,h) flattened [65536 x 64], Tw [64 comps x 64 j].
// Output transpose through LDS; coalesced short8 stores.
__global__ __launch_bounds__(256) void dft2(const bf16* __restrict__ qg,
                                            const bf16* __restrict__ kg,
                                            const bf16* __restrict__ Tw,
                                            bf16* __restrict__ Ab,
                                            int same_qk){
    __shared__ __align__(16) unsigned short Tl[64][68];
    int tid = threadIdx.x, wv = tid >> 6, lane = tid & 63;
    int qd = lane >> 4, n = lane & 15;
    int m0 = blockIdx.x*64 + wv*16;     // wave's 16 global rows (= 2 l x 8 h)
    const short* qp = (const short*)qg;
    const short* kp = (const short*)kg;
    const short* tw = (const short*)Tw;
    short8 aq0 = *(const short8*)&qp[(size_t)(m0+n)*64 + qd*8];
    short8 aq1 = *(const short8*)&qp[(size_t)(m0+n)*64 + 32 + qd*8];
    short8 bw[4][2];
    #pragma unroll
    for(int nt=0;nt<4;nt++){
        bw[nt][0] = *(const short8*)&tw[(size_t)(nt*16+n)*64 + qd*8];
        bw[nt][1] = *(const short8*)&tw[(size_t)(nt*16+n)*64 + 32 + qd*8];
    }
    floatx4 dq[4], dk[4];
    #pragma unroll
    for(int nt=0;nt<4;nt++){
        floatx4 a = {};
        a = __builtin_amdgcn_mfma_f32_16x16x32_bf16(aq0, bw[nt][0], a, 0,0,0);
        a = __builtin_amdgcn_mfma_f32_16x16x32_bf16(aq1, bw[nt][1], a, 0,0,0);
        dq[nt] = a;
    }
    if(same_qk){
        #pragma unroll
        for(int nt=0;nt<4;nt++) dk[nt] = dq[nt];
    }else{
        short8 ak0 = *(const short8*)&kp[(size_t)(m0+n)*64 + qd*8];
        short8 ak1 = *(const short8*)&kp[(size_t)(m0+n)*64 + 32 + qd*8];
        #pragma unroll
        for(int nt=0;nt<4;nt++){
            floatx4 a = {};
            a = __builtin_amdgcn_mfma_f32_16x16x32_bf16(ak0, bw[nt][0], a, 0,0,0);
            a = __builtin_amdgcn_mfma_f32_16x16x32_bf16(ak1, bw[nt][1], a, 0,0,0);
            dk[nt] = a;
        }
    }
    #pragma unroll
    for(int nt=0;nt<4;nt++){
        float o[4];
        #pragma unroll
        for(int r=0;r<4;r++){
            float a  = dq[nt][r], pa = __shfl_xor(a, 1);
            float c  = dk[nt][r], pc = __shfl_xor(c, 1);
            o[r] = (n & 1) ? (pa*c - a*pc) : (a*c + pa*pc);
        }
        float s = o[0]+o[1]+o[2]+o[3];
        s += __shfl_xor(s, 16);          // pair qd<->qd^1: all 8 h of same l
        float mean = s*0.125f;
        #pragma unroll
        for(int r=0;r<4;r++)
            Tl[wv*16 + qd*4 + r][nt*16 + n] = f2bu((o[r]-mean)*(1.f/512.f));
    }
    __syncthreads();
    // coalesced store: thread t -> h-slab (t>>5), row l_loc ((t&31)>>2), 32B chunk (t&3)
    int h2 = tid >> 5, lloc = (tid & 31) >> 2, c4 = tid & 3;
    int lr = lloc*8 + h2;
    int bI = blockIdx.x >> 7;
    int l  = (blockIdx.x & 127)*8 + lloc;
    union { ushort4v h[4]; short8 s[2]; } w;
    const unsigned short* src = &Tl[lr][c4*16];
    w.h[0] = *(const ushort4v*)(src);
    w.h[1] = *(const ushort4v*)(src+4);
    w.h[2] = *(const ushort4v*)(src+8);
    w.h[3] = *(const ushort4v*)(src+12);
    short* dp = (short*)Ab + ((size_t)bI*MM + (size_t)h2*LL + l)*GK + c4*16;
    *(short8*)dp       = w.s[0];
    *(short8*)(dp + 8) = w.s[1];
}

// Row "stats": writes -ln(S_m) directly (fused_pv uses it as MFMA C-init).
__global__ __launch_bounds__(256) void rowstats3(const bf16* __restrict__ Ab,
                                                 const bf16* __restrict__ Tg,
                                                 float* __restrict__ rs){
    __shared__ float red[4][64];
    int tid = threadIdx.x, wv = tid >> 6, lane = tid & 63;
    int q = lane >> 4, n = lane & 15;
    int m0 = blockIdx.x*64, bloc = blockIdx.y;
    const short* Abase = (const short*)(Ab + ((size_t)bloc*MM)*GK);
    const short* Tb = (const short*)Tg;
    short8 af[4][2];
    #pragma unroll
    for(int mg=0;mg<4;mg++){
        af[mg][0] = *(const short8*)&Abase[(size_t)(m0+mg*16+n)*GK + q*8];
        af[mg][1] = *(const short8*)&Abase[(size_t)(m0+mg*16+n)*GK + 32 + q*8];
    }
    float s[4][4] = {};
    #pragma unroll
    for(int nt=0;nt<16;nt++){
        int t = wv*256 + nt*16 + n;
        short8 b0 = *(const short8*)&Tb[(size_t)t*GK + q*8];
        short8 b1 = *(const short8*)&Tb[(size_t)t*GK + 32 + q*8];
        #pragma unroll
        for(int mg=0;mg<4;mg++){
            floatx4 d = {};
            d = __builtin_amdgcn_mfma_f32_16x16x32_bf16(af[mg][0], b0, d, 0,0,0);
            d = __builtin_amdgcn_mfma_f32_16x16x32_bf16(af[mg][1], b1, d, 0,0,0);
            #pragma unroll
            for(int r=0;r<4;r++) s[mg][r] += __expf(d[r]);
        }
    }
    #pragma unroll
    for(int o=1;o<16;o<<=1)
        #pragma unroll
        for(int mg=0;mg<4;mg++)
            #pragma unroll
            for(int r=0;r<4;r++) s[mg][r] += __shfl_xor(s[mg][r], o, 64);
    if(n == 0){
        #pragma unroll
        for(int mg=0;mg<4;mg++)
            #pragma unroll
            for(int r=0;r<4;r++) red[wv][mg*16 + q*4 + r] = s[mg][r];
    }
    __syncthreads();
    if(tid < 64)
        rs[(size_t)bloc*MM + m0 + tid] =
            -__logf(red[0][tid]+red[1][tid]+red[2][tid]+red[3][tid]);
}

// V-transpose: Vt[(b*8+h)*64 + c][j] = v[b][j][h*64+c]  (LDS-tiled, coalesced both sides)
__global__ __launch_bounds__(256) void vt_kernel(const bf16* __restrict__ v,
                                                 bf16* __restrict__ vt){
    __shared__ unsigned short T2[64][68];   // [c][j_loc]
    int jc = blockIdx.x, h = blockIdx.y, b = blockIdx.z;
    int tid = threadIdx.x;
    const unsigned short* src = (const unsigned short*)v + ((size_t)b*LL)*DD + (size_t)h*DH;
    int cq = tid & 15, jq = tid >> 4;       // thread: c-quad cq*4, 4 j rows
    #pragma unroll
    for(int jr=0;jr<4;jr++){
        int jl = jq*4 + jr;
        ushort4v vv = *(const ushort4v*)&src[(size_t)(jc*64 + jl)*DD + cq*4];
        T2[cq*4+0][jl] = vv.x;
        T2[cq*4+1][jl] = vv.y;
        T2[cq*4+2][jl] = vv.z;
        T2[cq*4+3][jl] = vv.w;
    }
    __syncthreads();
    int j4 = tid & 15, ct = tid >> 4;
    unsigned short* dstb = (unsigned short*)vt + ((size_t)(b*NH + h))*64*LL + (size_t)jc*64;
    #pragma unroll
    for(int cc=0;cc<4;cc++){
        int c = cc*16 + ct;
        *(ushort4v*)&dstb[(size_t)c*LL + j4*4] = *(const ushort4v*)&T2[c][j4*4];
    }
}

// Fused corr-recompute + softmax + PV (R5/R6 verified version, stride-68 union
// reads -- the PLS=72 b128 variant was an 8-way bank conflict, reverted).
__global__ __launch_bounds__(256, 2) void fused_pv(const bf16* __restrict__ Ab,
                                                   const bf16* __restrict__ Tg,
                                                   const float* __restrict__ rs,
                                                   const bf16* __restrict__ vt,
                                                   bf16* __restrict__ dst){
    __shared__ __align__(16) unsigned short AbS[2][64][68];  // [buf][j_loc][k]
    __shared__ __align__(16) unsigned short VsS[2][64][68];  // [buf][c][j_loc]
    __shared__ __align__(16) unsigned short Pl[128][68];     // [i_loc][j_loc] wave-private rows
    __shared__ float stS[LL];                                // -ln(S_j)
    int tid = threadIdx.x, wv = tid >> 6, lane = tid & 63;
    int q = lane >> 4, n = lane & 15;
    int id = blockIdx.x;                 // 0..511
    int xcd = id & 7, p = id >> 3;       // p: 0..63
    int pair = xcd*8 + (p & 7);          // all 8 i-splits of a pair on one XCD
    int i0 = (p >> 3) * 128;             // 8 i-splits x 128 rows
    int h = pair & 7, bloc = pair >> 3;
    const short* Abase = (const short*)(Ab + ((size_t)bloc*MM + (size_t)h*LL)*GK);
    const short* Tb = (const short*)Tg;
    const float* rsb = rs + (size_t)bloc*MM + (size_t)h*LL;
    const short* vtb = (const short*)(vt + (size_t)pair*64*LL);

    // stage -lnS once (coalesced float4)
    *(floatx4*)&stS[tid*4] = *(const floatx4*)&rsb[tid*4];

    // Tg fragments: 2 i-tiles per wave
    short8 tgf[2][2];
    #pragma unroll
    for(int t2=0;t2<2;t2++){
        tgf[t2][0] = *(const short8*)&Tb[(size_t)(i0+wv*32+t2*16+n)*GK + q*8];
        tgf[t2][1] = *(const short8*)&Tb[(size_t)(i0+wv*32+t2*16+n)*GK + 32 + q*8];
    }

    // staging map: thread -> row srow (0..63), 32B chunk sc (shorts)
    int srow = tid >> 2, sc = (tid & 3) * 16;
    const short* agp = &Abase[(size_t)srow*GK + sc];   // Ab[j0+srow][sc..]
    const short* vgp = &vtb[(size_t)srow*LL + sc];     // Vt[srow][j0+sc..]

    union S8 { short8 s; ushort4v h[2]; };

    // prologue: stage j-tile 0 into buffer 0
    {
        S8 a0,a1,v0,v1;
        a0.s = *(const short8*)agp;       a1.s = *(const short8*)(agp+8);
        v0.s = *(const short8*)vgp;       v1.s = *(const short8*)(vgp+8);
        *(ushort4v*)&AbS[0][srow][sc]    = a0.h[0];
        *(ushort4v*)&AbS[0][srow][sc+4]  = a0.h[1];
        *(ushort4v*)&AbS[0][srow][sc+8]  = a1.h[0];
        *(ushort4v*)&AbS[0][srow][sc+12] = a1.h[1];
        *(ushort4v*)&VsS[0][srow][sc]    = v0.h[0];
        *(ushort4v*)&VsS[0][srow][sc+4]  = v0.h[1];
        *(ushort4v*)&VsS[0][srow][sc+8]  = v1.h[0];
        *(ushort4v*)&VsS[0][srow][sc+12] = v1.h[1];
    }
    __syncthreads();

    floatx4 acc[4][2] = {};
    int cur = 0;
    for(int it=0; it<16; ++it){
        int j0 = it*64;
        // issue next-tile global loads EARLY (consumed after ~full iter of compute)
        S8 na0,na1,nv0,nv1;
        if(it < 15){
            na0.s = *(const short8*)(agp + (size_t)(j0+64)*GK);
            na1.s = *(const short8*)(agp + (size_t)(j0+64)*GK + 8);
            nv0.s = *(const short8*)(vgp + (j0+64));
            nv1.s = *(const short8*)(vgp + (j0+64) + 8);
        }
        // corr: P[j][i] = exp(corr - lnS_j); A-frags from LDS, shared across i-tiles
        #pragma unroll
        for(int tj=0;tj<4;tj++){
            S8 a0,a1;
            const unsigned short* ar = &AbS[cur][tj*16+n][0];
            a0.h[0] = *(const ushort4v*)&ar[q*8];
            a0.h[1] = *(const ushort4v*)&ar[q*8+4];
            a1.h[0] = *(const ushort4v*)&ar[32+q*8];
            a1.h[1] = *(const ushort4v*)&ar[32+q*8+4];
            floatx4 c0 = *(const floatx4*)&stS[j0 + tj*16 + q*4];
            #pragma unroll
            for(int t2=0;t2<2;t2++){
                floatx4 d = c0;
                d = __builtin_amdgcn_mfma_f32_16x16x32_bf16(a0.s, tgf[t2][0], d, 0,0,0);
                d = __builtin_amdgcn_mfma_f32_16x16x32_bf16(a1.s, tgf[t2][1], d, 0,0,0);
                ushort4v pk;
                pk.x = f2bu(__expf(d[0]));
                pk.y = f2bu(__expf(d[1]));
                pk.z = f2bu(__expf(d[2]));
                pk.w = f2bu(__expf(d[3]));
                *(ushort4v*)&Pl[wv*32 + t2*16 + n][tj*16 + q*4] = pk;
            }
        }
        // PV: out^T[c][i]; va from LDS VsS (shared across i-tiles), pf wave-private
        #pragma unroll
        for(int kc=0;kc<2;kc++){
            S8 va[4];
            #pragma unroll
            for(int cs=0;cs<4;cs++){
                const unsigned short* vp = &VsS[cur][cs*16+n][kc*32+q*8];
                va[cs].h[0] = *(const ushort4v*)vp;
                va[cs].h[1] = *(const ushort4v*)(vp+4);
            }
            #pragma unroll
            for(int t2=0;t2<2;t2++){
                S8 pf;
                const unsigned short* pp = &Pl[wv*32 + t2*16 + n][kc*32 + q*8];
                pf.h[0] = *(const ushort4v*)pp;
                pf.h[1] = *(const ushort4v*)(pp+4);
                #pragma unroll
                for(int cs=0;cs<4;cs++)
                    acc[cs][t2] = __builtin_amdgcn_mfma_f32_16x16x32_bf16(va[cs].s, pf.s, acc[cs][t2], 0,0,0);
            }
        }
        // write next stage LATE (global latency hidden under compute), then barrier
        if(it < 15){
            int nb = cur ^ 1;
            *(ushort4v*)&AbS[nb][srow][sc]    = na0.h[0];
            *(ushort4v*)&AbS[nb][srow][sc+4]  = na0.h[1];
            *(ushort4v*)&AbS[nb][srow][sc+8]  = na1.h[0];
            *(ushort4v*)&AbS[nb][srow][sc+12] = na1.h[1];
            *(ushort4v*)&VsS[nb][srow][sc]    = nv0.h[0];
            *(ushort4v*)&VsS[nb][srow][sc+4]  = nv0.h[1];
            *(ushort4v*)&VsS[nb][srow][sc+8]  = nv1.h[0];
            *(ushort4v*)&VsS[nb][srow][sc+12] = nv1.h[1];
        }
        __syncthreads();
        cur ^= 1;
    }
    // D[c][i]: c = cs*16 + q*4 + r, i = i0 + wv*32 + t2*16 + n
    bf16* db = dst + (size_t)bloc*LL*DD;
    #pragma unroll
    for(int t2=0;t2<2;t2++){
        int i = i0 + wv*32 + t2*16 + n;
        #pragma unroll
        for(int cs=0;cs<4;cs++){
            #pragma unroll
            for(int r=0;r<4;r++){
                int c = cs*16 + q*4 + r;
                db[(size_t)c*MM + h*LL + i] = f2b(acc[cs][t2][r]);
            }
        }
    }
}

// out = (seas + trend_sum) @ proj_w + proj_b, using pre-transposed pwT (f32).
__global__ __launch_bounds__(64) void final_kernel(const bf16* __restrict__ s,
                                                   const bf16* __restrict__ t,
                                                   const float* __restrict__ pwT,
                                                   const void* __restrict__ pbv,
                                                   const int* __restrict__ flag,
                                                   void* __restrict__ outv){
    bool f32 = (*flag != 0);
    int row = blockIdx.x;
    int lane = threadIdx.x;
    const short* sr = (const short*)s + (size_t)row*DD;
    const short* tr = (const short*)t + (size_t)row*DD;
    int j0 = lane*8;
    union { short8 v; unsigned short u[8]; } s8, t8;
    s8.v = *(const short8*)&sr[j0];
    t8.v = *(const short8*)&tr[j0];
    float dv[8];
    #pragma unroll
    for(int jj=0;jj<8;jj++) dv[jj] = bu2f(s8.u[jj]) + bu2f(t8.u[jj]);
    float acc[CO];
    #pragma unroll
    for(int c=0;c<CO;c++){
        floatx4 w0 = *(const floatx4*)&pwT[(size_t)c*DD + j0];
        floatx4 w1 = *(const floatx4*)&pwT[(size_t)c*DD + j0 + 4];
        acc[c] = dv[0]*w0[0] + dv[1]*w0[1] + dv[2]*w0[2] + dv[3]*w0[3]
               + dv[4]*w1[0] + dv[5]*w1[1] + dv[6]*w1[2] + dv[7]*w1[3];
    }
    #pragma unroll
    for(int c=0;c<CO;c++){
        float vsum = acc[c];
        for(int off=32;off;off>>=1) vsum += __shfl_down(vsum,off,64);
        if(lane==0){
            float bias = f32 ? ((const float*)pbv)[c] : b2f(((const bf16*)pbv)[c]);
            float o = vsum + bias;
            if(f32) ((float*)outv)[(size_t)row*CO + c] = o;
            else    ((bf16*)outv)[(size_t)row*CO + c] = f2b(o);
        }
    }
}

extern "C" void kernel_launch(void* const* d_in, const int* in_sizes, int n_in,
                              void* d_out, int out_size, void* d_ws, size_t ws_size,
                              hipStream_t stream){
    const void* x_enc  = d_in[0];
    const void* x_dec  = d_in[2];
    const void* enc_w  = d_in[4];
    const void* enc_b  = d_in[5];
    const void* dec_w  = d_in[6];
    const void* dec_b  = d_in[7];
    const void* proj_w = d_in[8];
    const void* proj_b = d_in[9];

    int*  flag = (int*)d_ws;
    const size_t NE = (size_t)BB*LL*DD;
    bf16* A  = (bf16*)((char*)d_ws + 1024);
    bf16* Bf = A  + NE;
    bf16* C  = Bf + NE;
    bf16* T  = C  + NE;
    bf16* Tg = T  + NE;                              // [1024][64]
    bf16* Tw = Tg + (size_t)LL*GK;                   // [64][64]
    float* xs = (float*)(Tw + 64*64);
    float* xm = xs + (size_t)BB*LL*7;
    bf16* Ab  = (bf16*)(xm + (size_t)BB*LL*7);       // [BB][MM][GK]
    float* rs = (float*)(Ab + (size_t)BB*MM*GK);     // [BB][MM], holds -ln(S)
    bf16* Vt  = (bf16*)(rs + (size_t)BB*MM);         // [BB*NH*64][LL]
    float* pwT = (float*)(Vt + (size_t)BB*NH*64*LL); // [CO][DD]

    sniff_kernel<<<1,64,0,stream>>>((const unsigned*)x_enc, flag);
    prep_kernel<<<143,512,0,stream>>>(Tg, Tw, proj_w, flag, pwT);

    auto autocorr = [&](const bf16* q, const bf16* kv, bf16* dst){
        vt_kernel<<<dim3(16, NH, BB), 256, 0, stream>>>(kv, Vt);
        dft2<<<1024, 256, 0, stream>>>(q, kv, Tw, Ab, (q==kv) ? 1 : 0);
        rowstats3<<<dim3(128, BB), 256, 0, stream>>>(Ab, Tg, rs);
        fused_pv<<<512, 256, 0, stream>>>(Ab, Tg, rs, Vt, dst);
    };

    const int MA_GRID = (BB*LL*7 + 255)/256;
    ma7_kernel<<<MA_GRID,256,0,stream>>>(x_enc, flag, xs, xm);
    embed2_kernel<<<16384,256,0,stream>>>(xs, xm, enc_w, enc_b, flag, A, T, 0);
    autocorr(A, A, Bf);      // layer 1 -> Bf
    autocorr(Bf, Bf, A);     // layer 2 -> A (= enc_seasonal out)

    ma7_kernel<<<MA_GRID,256,0,stream>>>(x_dec, flag, xs, xm);
    embed2_kernel<<<16384,256,0,stream>>>(xs, xm, dec_w, dec_b, flag, Bf, T, 1);
    autocorr(Bf, A, C);      // cross layer -> C

    final_kernel<<<BB*LL,64,0,stream>>>(C, T, pwT, proj_b, flag, d_out);
}